// Round 6
// baseline (1405.456 us; speedup 1.0000x reference)
//
#include <hip/hip_runtime.h>
#include <hip/hip_bf16.h>

// Problem constants
#define EMBED 1024
#define NH 16
#define HD 64
#define TSEQ 1024
#define SSEQ 1024
#define BATCH 4
#define AVGN ((size_t)BATCH * TSEQ * SSEQ)

using short8   = __attribute__((ext_vector_type(8))) short;
using float4v  = __attribute__((ext_vector_type(4))) float;
using ushort4v = __attribute__((ext_vector_type(4))) unsigned short;

__device__ __forceinline__ unsigned short f2bf(float f) {
    union { float f; unsigned int u; } v; v.f = f;
    unsigned int r = v.u + 0x7fffu + ((v.u >> 16) & 1u);   // RNE
    return (unsigned short)(r >> 16);
}
__device__ __forceinline__ float bf2f(unsigned short u) {
    union { unsigned int u; float f; } v; v.u = ((unsigned int)u) << 16;
    return v.f;
}

// ---------------------------------------------------------------------------
// NT GEMM (fp32, validated round 3): C = A*W^T + bias, optional scale.
// ---------------------------------------------------------------------------
__global__ __launch_bounds__(256) void gemm_nt(
    const float* __restrict__ A0, const float* __restrict__ A1,
    const float* __restrict__ A2,
    const float* __restrict__ W, const float* __restrict__ bias,
    float* __restrict__ C, int M, int N, int K, int scaleN, float scale)
{
    __shared__ float As[16][128 + 4];
    __shared__ float Bs[16][128 + 4];

    const int m0 = blockIdx.y * 128;
    const int n0 = blockIdx.x * 128;
    const float* A = (n0 < EMBED) ? A0 : (n0 < 2 * EMBED ? A1 : A2);

    const int tid = threadIdx.x;
    const int ty = tid >> 4;
    const int tx = tid & 15;
    const int lr = tid >> 1;
    const int lk = (tid & 1) * 8;

    const float* Ap = A + (size_t)(m0 + lr) * K + lk;
    const float* Wp = W + (size_t)(n0 + lr) * K + lk;

    float acc[8][8] = {};

    for (int k0 = 0; k0 < K; k0 += 16) {
        const float4 a0 = *(const float4*)(Ap + k0);
        const float4 a1 = *(const float4*)(Ap + k0 + 4);
        const float4 b0 = *(const float4*)(Wp + k0);
        const float4 b1 = *(const float4*)(Wp + k0 + 4);
        __syncthreads();
        As[lk + 0][lr] = a0.x; As[lk + 1][lr] = a0.y;
        As[lk + 2][lr] = a0.z; As[lk + 3][lr] = a0.w;
        As[lk + 4][lr] = a1.x; As[lk + 5][lr] = a1.y;
        As[lk + 6][lr] = a1.z; As[lk + 7][lr] = a1.w;
        Bs[lk + 0][lr] = b0.x; Bs[lk + 1][lr] = b0.y;
        Bs[lk + 2][lr] = b0.z; Bs[lk + 3][lr] = b0.w;
        Bs[lk + 4][lr] = b1.x; Bs[lk + 5][lr] = b1.y;
        Bs[lk + 6][lr] = b1.z; Bs[lk + 7][lr] = b1.w;
        __syncthreads();

        #pragma unroll
        for (int kk = 0; kk < 16; ++kk) {
            const float4 av0 = *(const float4*)&As[kk][ty * 4];
            const float4 av1 = *(const float4*)&As[kk][64 + ty * 4];
            const float4 bv0 = *(const float4*)&Bs[kk][tx * 4];
            const float4 bv1 = *(const float4*)&Bs[kk][64 + tx * 4];
            const float ar[8] = {av0.x, av0.y, av0.z, av0.w,
                                 av1.x, av1.y, av1.z, av1.w};
            const float br[8] = {bv0.x, bv0.y, bv0.z, bv0.w,
                                 bv1.x, bv1.y, bv1.z, bv1.w};
            #pragma unroll
            for (int i = 0; i < 8; ++i)
                #pragma unroll
                for (int j = 0; j < 8; ++j)
                    acc[i][j] += ar[i] * br[j];
        }
    }

    #pragma unroll
    for (int ih = 0; ih < 2; ++ih) {
        #pragma unroll
        for (int i = 0; i < 4; ++i) {
            const int m = m0 + ih * 64 + ty * 4 + i;
            #pragma unroll
            for (int jh = 0; jh < 2; ++jh) {
                const int n = n0 + jh * 64 + tx * 4;
                const float s = (n < scaleN) ? scale : 1.0f;
                float4 r;
                r.x = (acc[ih * 4 + i][jh * 4 + 0] + bias[n + 0]) * s;
                r.y = (acc[ih * 4 + i][jh * 4 + 1] + bias[n + 1]) * s;
                r.z = (acc[ih * 4 + i][jh * 4 + 2] + bias[n + 2]) * s;
                r.w = (acc[ih * 4 + i][jh * 4 + 3] + bias[n + 3]) * s;
                *(float4*)&C[(size_t)m * N + n] = r;
            }
        }
    }
}

// ---------------------------------------------------------------------------
// BISECT kernel: MFMA QK^T (hi/lo bf16 split -> ~fp32 scores) + VALU PV.
// Block = (b, 16 q-rows, head-group g of HG heads), 256 threads / 4 waves.
// Wave w owns s-columns {w*16 + (lane&15)} of each 64-wide s-tile.
// Two-pass softmax: pass1 lane-local online (m,l), merged via shfl + LDS.
// Pass2: scores again via MFMA -> exact normalized P -> plain LDS Ps[16][68];
// V staged fp32 Vs[64][68]; PV per-thread VALU (row=tid>>4, d-slice (tid&15)*4)
// -- the round-3-validated pattern. No Vt/Pb/Osum machinery.
// avg: block owns [b, t0:t0+16, :] strip; plain RMW; group 0 -> avg (d_out),
// groups >0 -> ws partials; reduce_avg sums them (only when G > 1).
// ---------------------------------------------------------------------------
__global__ __launch_bounds__(256) void attn_mfma_qk(
    const float* __restrict__ qkv,
    const int* __restrict__ pad,
    const float* __restrict__ amask,
    float* __restrict__ attn_out,
    float* __restrict__ avg,
    float* __restrict__ parts,
    int HG)
{
    __shared__ __align__(16) unsigned short Kh[64 * 64];  // [s][d] hi, swizzled
    __shared__ __align__(16) unsigned short Kl[64 * 64];  // [s][d] lo, swizzled
    __shared__ __align__(16) float Vs[64][68];            // [s][d] fp32, natural
    __shared__ __align__(16) float Ps[16][68];            // [t][s] fp32, natural
    __shared__ float Mred[2][4][16];

    const int bid = blockIdx.x;
    const int tb  = bid & 63;
    const int b   = (bid >> 6) & 3;
    const int g   = bid >> 8;
    const int t0  = tb * 16;
    const int tid = threadIdx.x;
    const int w   = tid >> 6;
    const int l15 = tid & 15;
    const int l4  = (tid & 63) >> 4;

    float* dst = (g == 0) ? avg : parts + (size_t)(g - 1) * AVGN;
    const float inv_H = 1.0f / NH;
    const int h0 = g * HG;

    const int ks_row = tid >> 2;               // K/V-stage s row 0..63
    const int ks_swz = 8 * (ks_row & 7);
    const int brow = w * 16 + l15;             // K-frag row this lane reads
    const int bswz = 8 * (brow & 7);
    const int prow = tid >> 4;                 // PV row 0..15
    const int pd4  = (tid & 15) * 4;           // PV d-slice

    for (int h = h0; h < h0 + HG; ++h) {
        // ---- Q A-frags (hi/lo): global -> registers ----
        short8 qh[2], ql[2];
        {
            const float* qrow = qkv + ((size_t)((t0 + l15) * BATCH + b)) * 3072 + h * HD;
            #pragma unroll
            for (int ks = 0; ks < 2; ++ks) {
                const float4 x0 = *(const float4*)(qrow + ks * 32 + l4 * 8);
                const float4 x1 = *(const float4*)(qrow + ks * 32 + l4 * 8 + 4);
                const float xf[8] = {x0.x, x0.y, x0.z, x0.w, x1.x, x1.y, x1.z, x1.w};
                short8 qhv, qlv;
                #pragma unroll
                for (int j = 0; j < 8; ++j) {
                    const unsigned short hi = f2bf(xf[j]);
                    qhv[j] = (short)hi;
                    qlv[j] = (short)f2bf(xf[j] - bf2f(hi));
                }
                qh[ks] = qhv; ql[ks] = qlv;
            }
        }

        float ml[4], ll[4];
        #pragma unroll
        for (int r = 0; r < 4; ++r) { ml[r] = -1e30f; ll[r] = 0.f; }

        // ================= pass 1: lane-local online (m,l) =================
        for (int st = 0; st < 16; ++st) {
            const int s0 = st * 64;
            __syncthreads();
            {   // stage K tile, hi/lo
                const float* krow = qkv + ((size_t)((s0 + ks_row) * BATCH + b)) * 3072
                                  + EMBED + h * HD;
                #pragma unroll
                for (int it = 0; it < 4; ++it) {
                    const int d = (tid & 3) * 4 + it * 16;
                    const float4 x = *(const float4*)(krow + d);
                    const float xf[4] = {x.x, x.y, x.z, x.w};
                    ushort4v uh, ul;
                    #pragma unroll
                    for (int j = 0; j < 4; ++j) {
                        const unsigned short hi = f2bf(xf[j]);
                        uh[j] = hi;
                        ul[j] = f2bf(xf[j] - bf2f(hi));
                    }
                    *(ushort4v*)&Kh[ks_row * 64 + (d ^ ks_swz)] = uh;
                    *(ushort4v*)&Kl[ks_row * 64 + (d ^ ks_swz)] = ul;
                }
            }
            __syncthreads();

            const short8 kh0 = *(const short8*)&Kh[brow * 64 + ((l4 * 8) ^ bswz)];
            const short8 kh1 = *(const short8*)&Kh[brow * 64 + ((32 + l4 * 8) ^ bswz)];
            const short8 kl0 = *(const short8*)&Kl[brow * 64 + ((l4 * 8) ^ bswz)];
            const short8 kl1 = *(const short8*)&Kl[brow * 64 + ((32 + l4 * 8) ^ bswz)];
            float4v c = {0.f, 0.f, 0.f, 0.f};
            c = __builtin_amdgcn_mfma_f32_16x16x32_bf16(qh[0], kh0, c, 0, 0, 0);
            c = __builtin_amdgcn_mfma_f32_16x16x32_bf16(qh[1], kh1, c, 0, 0, 0);
            c = __builtin_amdgcn_mfma_f32_16x16x32_bf16(ql[0], kh0, c, 0, 0, 0);
            c = __builtin_amdgcn_mfma_f32_16x16x32_bf16(ql[1], kh1, c, 0, 0, 0);
            c = __builtin_amdgcn_mfma_f32_16x16x32_bf16(qh[0], kl0, c, 0, 0, 0);
            c = __builtin_amdgcn_mfma_f32_16x16x32_bf16(qh[1], kl1, c, 0, 0, 0);

            const int scol = s0 + w * 16 + l15;
            const float padd = pad[b * SSEQ + scol] ? -1e30f : 0.f;
            #pragma unroll
            for (int r = 0; r < 4; ++r) {
                const int trow = t0 + l4 * 4 + r;
                const float sf = c[r] + amask[(size_t)trow * SSEQ + scol] + padd;
                const float mn = fmaxf(ml[r], sf);
                ll[r] = ll[r] * __expf(ml[r] - mn) + __expf(sf - mn);
                ml[r] = mn;
            }
        }

        // merge across the 16 lanes of each column group
        #pragma unroll
        for (int off = 1; off < 16; off <<= 1) {
            #pragma unroll
            for (int r = 0; r < 4; ++r) {
                const float mo = __shfl_xor(ml[r], off);
                const float lo = __shfl_xor(ll[r], off);
                const float mn = fmaxf(ml[r], mo);
                ll[r] = ll[r] * __expf(ml[r] - mn) + lo * __expf(mo - mn);
                ml[r] = mn;
            }
        }
        __syncthreads();
        if (l15 == 0) {
            #pragma unroll
            for (int r = 0; r < 4; ++r) {
                Mred[0][w][l4 * 4 + r] = ml[r];
                Mred[1][w][l4 * 4 + r] = ll[r];
            }
        }
        __syncthreads();

        float mfin[4], invl[4];
        #pragma unroll
        for (int r = 0; r < 4; ++r) {
            const int row = l4 * 4 + r;
            float m = Mred[0][0][row];
            m = fmaxf(m, Mred[0][1][row]);
            m = fmaxf(m, Mred[0][2][row]);
            m = fmaxf(m, Mred[0][3][row]);
            float L = 0.f;
            #pragma unroll
            for (int w2 = 0; w2 < 4; ++w2)
                L += Mred[1][w2][row] * __expf(Mred[0][w2][row] - m);
            mfin[r] = m;
            invl[r] = 1.0f / L;
        }

        // ================= pass 2: P (MFMA scores), avg, VALU PV ============
        float o[4] = {0.f, 0.f, 0.f, 0.f};

        for (int st = 0; st < 16; ++st) {
            const int s0 = st * 64;
            __syncthreads();   // (A) prev tile's PV reads of Ps/Vs complete
            {   // stage K tile hi/lo + V tile fp32
                const float* base = qkv + ((size_t)((s0 + ks_row) * BATCH + b)) * 3072
                                  + h * HD;
                const float* krow = base + EMBED;
                const float* vrow = base + 2 * EMBED;
                #pragma unroll
                for (int it = 0; it < 4; ++it) {
                    const int d = (tid & 3) * 4 + it * 16;
                    const float4 x = *(const float4*)(krow + d);
                    const float xf[4] = {x.x, x.y, x.z, x.w};
                    ushort4v uh, ul;
                    #pragma unroll
                    for (int j = 0; j < 4; ++j) {
                        const unsigned short hi = f2bf(xf[j]);
                        uh[j] = hi;
                        ul[j] = f2bf(xf[j] - bf2f(hi));
                    }
                    *(ushort4v*)&Kh[ks_row * 64 + (d ^ ks_swz)] = uh;
                    *(ushort4v*)&Kl[ks_row * 64 + (d ^ ks_swz)] = ul;
                    *(float4*)&Vs[ks_row][d] = *(const float4*)(vrow + d);
                }
            }
            __syncthreads();   // (B) staging visible

            const short8 kh0 = *(const short8*)&Kh[brow * 64 + ((l4 * 8) ^ bswz)];
            const short8 kh1 = *(const short8*)&Kh[brow * 64 + ((32 + l4 * 8) ^ bswz)];
            const short8 kl0 = *(const short8*)&Kl[brow * 64 + ((l4 * 8) ^ bswz)];
            const short8 kl1 = *(const short8*)&Kl[brow * 64 + ((32 + l4 * 8) ^ bswz)];
            float4v c = {0.f, 0.f, 0.f, 0.f};
            c = __builtin_amdgcn_mfma_f32_16x16x32_bf16(qh[0], kh0, c, 0, 0, 0);
            c = __builtin_amdgcn_mfma_f32_16x16x32_bf16(qh[1], kh1, c, 0, 0, 0);
            c = __builtin_amdgcn_mfma_f32_16x16x32_bf16(ql[0], kh0, c, 0, 0, 0);
            c = __builtin_amdgcn_mfma_f32_16x16x32_bf16(ql[1], kh1, c, 0, 0, 0);
            c = __builtin_amdgcn_mfma_f32_16x16x32_bf16(qh[0], kl0, c, 0, 0, 0);
            c = __builtin_amdgcn_mfma_f32_16x16x32_bf16(qh[1], kl1, c, 0, 0, 0);

            const int scol = s0 + w * 16 + l15;
            const float padd = pad[b * SSEQ + scol] ? -1e30f : 0.f;
            float p[4];
            #pragma unroll
            for (int r = 0; r < 4; ++r) {
                const int trow = t0 + l4 * 4 + r;
                const float sf = c[r] + amask[(size_t)trow * SSEQ + scol] + padd;
                p[r] = __expf(sf - mfin[r]) * invl[r];
            }

            // avg strip RMW (no atomics: block owns the strip for its heads)
            #pragma unroll
            for (int r = 0; r < 4; ++r) {
                float* ap = dst + ((size_t)(b * TSEQ + t0 + l4 * 4 + r)) * SSEQ + scol;
                if (h == h0) *ap = p[r] * inv_H;
                else         *ap = *ap + p[r] * inv_H;
            }

            // P -> plain LDS (rows l4*4+r, col w*16+l15)
            #pragma unroll
            for (int r = 0; r < 4; ++r)
                Ps[l4 * 4 + r][w * 16 + l15] = p[r];

            __syncthreads();   // (C) Ps visible to all waves

            // VALU PV: thread (prow, pd4..pd4+3) over all 64 s of the tile
            #pragma unroll
            for (int s4 = 0; s4 < 64; s4 += 4) {
                const float4 ps = *(const float4*)&Ps[prow][s4];
                const float4 v0 = *(const float4*)&Vs[s4 + 0][pd4];
                const float4 v1 = *(const float4*)&Vs[s4 + 1][pd4];
                const float4 v2 = *(const float4*)&Vs[s4 + 2][pd4];
                const float4 v3 = *(const float4*)&Vs[s4 + 3][pd4];
                o[0] += ps.x * v0.x + ps.y * v1.x + ps.z * v2.x + ps.w * v3.x;
                o[1] += ps.x * v0.y + ps.y * v1.y + ps.z * v2.y + ps.w * v3.y;
                o[2] += ps.x * v0.z + ps.y * v1.z + ps.z * v2.z + ps.w * v3.z;
                o[3] += ps.x * v0.w + ps.y * v1.w + ps.z * v2.w + ps.w * v3.w;
            }
        }

        *(float4*)&attn_out[((size_t)((t0 + prow) * BATCH + b)) * EMBED + h * HD + pd4]
            = make_float4(o[0], o[1], o[2], o[3]);
    }
}

// ---------------------------------------------------------------------------
__global__ __launch_bounds__(256) void reduce_avg(
    float* __restrict__ avg, const float* __restrict__ parts, int nparts)
{
    const size_t n4 = AVGN / 4;
    size_t i = (size_t)blockIdx.x * blockDim.x + threadIdx.x;
    const size_t stride = (size_t)gridDim.x * blockDim.x;
    for (; i < n4; i += stride) {
        float4 a = ((const float4*)avg)[i];
        for (int g = 0; g < nparts; ++g) {
            const float4 p = ((const float4*)(parts + (size_t)g * AVGN))[i];
            a.x += p.x; a.y += p.y; a.z += p.z; a.w += p.w;
        }
        ((float4*)avg)[i] = a;
    }
}

// ---------------------------------------------------------------------------
extern "C" void kernel_launch(void* const* d_in, const int* in_sizes, int n_in,
                              void* d_out, int out_size, void* d_ws, size_t ws_size,
                              hipStream_t stream) {
    const float* query = (const float*)d_in[0];
    const float* key   = (const float*)d_in[1];
    const float* value = (const float*)d_in[2];
    const int*   pad   = (const int*)d_in[3];
    const float* amask = (const float*)d_in[4];
    const float* wqkv  = (const float*)d_in[5];
    const float* bqkv  = (const float*)d_in[6];
    const float* wout  = (const float*)d_in[7];
    const float* bout  = (const float*)d_in[8];

    float* out = (float*)d_out;
    float* avg = out + (size_t)TSEQ * BATCH * EMBED;

    float* qkv   = (float*)d_ws;
    float* attn  = qkv + (size_t)(TSEQ * BATCH) * (3 * EMBED);
    float* parts = attn + (size_t)(TSEQ * BATCH) * EMBED;

    const size_t base_bytes = ((size_t)(TSEQ * BATCH) * (3 * EMBED)
                             + (size_t)(TSEQ * BATCH) * EMBED) * sizeof(float);
    int G = 1;   // head groups, adaptive to workspace (G=1 needs 64MB, proven)
    if (ws_size >= base_bytes + 3 * AVGN * sizeof(float)) G = 4;
    else if (ws_size >= base_bytes + 1 * AVGN * sizeof(float)) G = 2;

    const int M = TSEQ * BATCH;
    const float scaling = 0.125f;

    dim3 g1(3 * EMBED / 128, M / 128);
    gemm_nt<<<g1, 256, 0, stream>>>(query, key, value, wqkv, bqkv, qkv,
                                    M, 3 * EMBED, EMBED, EMBED, scaling);

    attn_mfma_qk<<<dim3(256 * G), 256, 0, stream>>>(qkv, pad, amask, attn, avg,
                                                    parts, NH / G);

    if (G > 1) reduce_avg<<<1024, 256, 0, stream>>>(avg, parts, G - 1);

    dim3 g3(EMBED / 128, M / 128);
    gemm_nt<<<g3, 256, 0, stream>>>(attn, attn, attn, wout, bout, out,
                                    M, EMBED, EMBED, 0, 1.f);
}

// Round 7
// 1269.558 us; speedup vs baseline: 1.1070x; 1.1070x over previous
//
#include <hip/hip_runtime.h>
#include <hip/hip_bf16.h>

// Problem constants
#define EMBED 1024
#define NH 16
#define HD 64
#define TSEQ 1024
#define SSEQ 1024
#define BATCH 4

using short8   = __attribute__((ext_vector_type(8))) short;
using float4v  = __attribute__((ext_vector_type(4))) float;
using ushort4v = __attribute__((ext_vector_type(4))) unsigned short;

__device__ __forceinline__ unsigned short f2bf(float f) {
    union { float f; unsigned int u; } v; v.f = f;
    unsigned int r = v.u + 0x7fffu + ((v.u >> 16) & 1u);   // RNE
    return (unsigned short)(r >> 16);
}
__device__ __forceinline__ float bf2f(unsigned short u) {
    union { unsigned int u; float f; } v; v.u = ((unsigned int)u) << 16;
    return v.f;
}

// ---------------------------------------------------------------------------
// NT GEMM (fp32, validated round 3): C = A*W^T + bias, optional scale.
// ---------------------------------------------------------------------------
__global__ __launch_bounds__(256) void gemm_nt(
    const float* __restrict__ A0, const float* __restrict__ A1,
    const float* __restrict__ A2,
    const float* __restrict__ W, const float* __restrict__ bias,
    float* __restrict__ C, int M, int N, int K, int scaleN, float scale)
{
    __shared__ float As[16][128 + 4];
    __shared__ float Bs[16][128 + 4];

    const int m0 = blockIdx.y * 128;
    const int n0 = blockIdx.x * 128;
    const float* A = (n0 < EMBED) ? A0 : (n0 < 2 * EMBED ? A1 : A2);

    const int tid = threadIdx.x;
    const int ty = tid >> 4;
    const int tx = tid & 15;
    const int lr = tid >> 1;
    const int lk = (tid & 1) * 8;

    const float* Ap = A + (size_t)(m0 + lr) * K + lk;
    const float* Wp = W + (size_t)(n0 + lr) * K + lk;

    float acc[8][8] = {};

    for (int k0 = 0; k0 < K; k0 += 16) {
        const float4 a0 = *(const float4*)(Ap + k0);
        const float4 a1 = *(const float4*)(Ap + k0 + 4);
        const float4 b0 = *(const float4*)(Wp + k0);
        const float4 b1 = *(const float4*)(Wp + k0 + 4);
        __syncthreads();
        As[lk + 0][lr] = a0.x; As[lk + 1][lr] = a0.y;
        As[lk + 2][lr] = a0.z; As[lk + 3][lr] = a0.w;
        As[lk + 4][lr] = a1.x; As[lk + 5][lr] = a1.y;
        As[lk + 6][lr] = a1.z; As[lk + 7][lr] = a1.w;
        Bs[lk + 0][lr] = b0.x; Bs[lk + 1][lr] = b0.y;
        Bs[lk + 2][lr] = b0.z; Bs[lk + 3][lr] = b0.w;
        Bs[lk + 4][lr] = b1.x; Bs[lk + 5][lr] = b1.y;
        Bs[lk + 6][lr] = b1.z; Bs[lk + 7][lr] = b1.w;
        __syncthreads();

        #pragma unroll
        for (int kk = 0; kk < 16; ++kk) {
            const float4 av0 = *(const float4*)&As[kk][ty * 4];
            const float4 av1 = *(const float4*)&As[kk][64 + ty * 4];
            const float4 bv0 = *(const float4*)&Bs[kk][tx * 4];
            const float4 bv1 = *(const float4*)&Bs[kk][64 + tx * 4];
            const float ar[8] = {av0.x, av0.y, av0.z, av0.w,
                                 av1.x, av1.y, av1.z, av1.w};
            const float br[8] = {bv0.x, bv0.y, bv0.z, bv0.w,
                                 bv1.x, bv1.y, bv1.z, bv1.w};
            #pragma unroll
            for (int i = 0; i < 8; ++i)
                #pragma unroll
                for (int j = 0; j < 8; ++j)
                    acc[i][j] += ar[i] * br[j];
        }
    }

    #pragma unroll
    for (int ih = 0; ih < 2; ++ih) {
        #pragma unroll
        for (int i = 0; i < 4; ++i) {
            const int m = m0 + ih * 64 + ty * 4 + i;
            #pragma unroll
            for (int jh = 0; jh < 2; ++jh) {
                const int n = n0 + jh * 64 + tx * 4;
                const float s = (n < scaleN) ? scale : 1.0f;
                float4 r;
                r.x = (acc[ih * 4 + i][jh * 4 + 0] + bias[n + 0]) * s;
                r.y = (acc[ih * 4 + i][jh * 4 + 1] + bias[n + 1]) * s;
                r.z = (acc[ih * 4 + i][jh * 4 + 2] + bias[n + 2]) * s;
                r.w = (acc[ih * 4 + i][jh * 4 + 3] + bias[n + 3]) * s;
                *(float4*)&C[(size_t)m * N + n] = r;
            }
        }
    }
}

// ---------------------------------------------------------------------------
// Kernel A: per-head single-pass flash attention.
// Block = (b, h, 16 q-rows); grid 4096. MFMA QK^T (hi/lo split, validated r6);
// online softmax with per-tile cross-wave row-max sync; VALU PV (validated r6
// mapping) with per-tile O rescale; final O/L. Stores per-row m, L to ws for
// the separate avg kernel. No head loop, no avg RMW.
// ---------------------------------------------------------------------------
__global__ __launch_bounds__(256) void attn_flash(
    const float* __restrict__ qkv,
    const int* __restrict__ pad,
    const float* __restrict__ amask,
    float* __restrict__ attn_out,
    float* __restrict__ mfin_out,   // [B*NH*T]
    float* __restrict__ lfin_out)   // [B*NH*T]
{
    __shared__ __align__(16) unsigned short Kh[64 * 64];  // [s][d] hi, swizzled
    __shared__ __align__(16) unsigned short Kl[64 * 64];  // [s][d] lo, swizzled
    __shared__ __align__(16) float Vs[64][68];            // [s][d] fp32
    __shared__ __align__(16) float Ps[16][68];            // [t][s] unnormalized p
    __shared__ float Mtile[4][16];                        // per-wave row max
    __shared__ float Sc[16];                              // per-row rescale
    __shared__ float Lred[4][16];
    __shared__ float Lfin[16];

    const int bid = blockIdx.x;
    const int tb  = bid & 63;
    const int b   = (bid >> 6) & 3;
    const int h   = bid >> 8;
    const int t0  = tb * 16;
    const int tid = threadIdx.x;
    const int w   = tid >> 6;
    const int l15 = tid & 15;
    const int l4  = (tid & 63) >> 4;

    const int ks_row = tid >> 2;
    const int ks_swz = 8 * (ks_row & 7);
    const int brow = w * 16 + l15;
    const int bswz = 8 * (brow & 7);
    const int prow = tid >> 4;
    const int pd4  = (tid & 15) * 4;

    // ---- Q A-frags (hi/lo): global -> registers (validated r6) ----
    short8 qh[2], ql[2];
    {
        const float* qrow = qkv + ((size_t)((t0 + l15) * BATCH + b)) * 3072 + h * HD;
        #pragma unroll
        for (int ks = 0; ks < 2; ++ks) {
            const float4 x0 = *(const float4*)(qrow + ks * 32 + l4 * 8);
            const float4 x1 = *(const float4*)(qrow + ks * 32 + l4 * 8 + 4);
            const float xf[8] = {x0.x, x0.y, x0.z, x0.w, x1.x, x1.y, x1.z, x1.w};
            short8 qhv, qlv;
            #pragma unroll
            for (int j = 0; j < 8; ++j) {
                const unsigned short hi = f2bf(xf[j]);
                qhv[j] = (short)hi;
                qlv[j] = (short)f2bf(xf[j] - bf2f(hi));
            }
            qh[ks] = qhv; ql[ks] = qlv;
        }
    }

    float m_run[4], l_run[4];
    #pragma unroll
    for (int r = 0; r < 4; ++r) { m_run[r] = -1e30f; l_run[r] = 0.f; }
    float o[4] = {0.f, 0.f, 0.f, 0.f};

    for (int st = 0; st < 16; ++st) {
        const int s0 = st * 64;
        __syncthreads();   // prev tile's Ps/Vs/Sc reads complete
        {   // stage K hi/lo + V (validated r6 pass-2 staging)
            const float* base = qkv + ((size_t)((s0 + ks_row) * BATCH + b)) * 3072
                              + h * HD;
            const float* krow = base + EMBED;
            const float* vrow = base + 2 * EMBED;
            #pragma unroll
            for (int it = 0; it < 4; ++it) {
                const int d = (tid & 3) * 4 + it * 16;
                const float4 x = *(const float4*)(krow + d);
                const float xf[4] = {x.x, x.y, x.z, x.w};
                ushort4v uh, ul;
                #pragma unroll
                for (int j = 0; j < 4; ++j) {
                    const unsigned short hi = f2bf(xf[j]);
                    uh[j] = hi;
                    ul[j] = f2bf(xf[j] - bf2f(hi));
                }
                *(ushort4v*)&Kh[ks_row * 64 + (d ^ ks_swz)] = uh;
                *(ushort4v*)&Kl[ks_row * 64 + (d ^ ks_swz)] = ul;
                *(float4*)&Vs[ks_row][d] = *(const float4*)(vrow + d);
            }
        }
        __syncthreads();

        const short8 kh0 = *(const short8*)&Kh[brow * 64 + ((l4 * 8) ^ bswz)];
        const short8 kh1 = *(const short8*)&Kh[brow * 64 + ((32 + l4 * 8) ^ bswz)];
        const short8 kl0 = *(const short8*)&Kl[brow * 64 + ((l4 * 8) ^ bswz)];
        const short8 kl1 = *(const short8*)&Kl[brow * 64 + ((32 + l4 * 8) ^ bswz)];
        float4v c = {0.f, 0.f, 0.f, 0.f};
        c = __builtin_amdgcn_mfma_f32_16x16x32_bf16(qh[0], kh0, c, 0, 0, 0);
        c = __builtin_amdgcn_mfma_f32_16x16x32_bf16(qh[1], kh1, c, 0, 0, 0);
        c = __builtin_amdgcn_mfma_f32_16x16x32_bf16(ql[0], kh0, c, 0, 0, 0);
        c = __builtin_amdgcn_mfma_f32_16x16x32_bf16(ql[1], kh1, c, 0, 0, 0);
        c = __builtin_amdgcn_mfma_f32_16x16x32_bf16(qh[0], kl0, c, 0, 0, 0);
        c = __builtin_amdgcn_mfma_f32_16x16x32_bf16(qh[1], kl1, c, 0, 0, 0);

        const int scol = s0 + w * 16 + l15;
        const float padd = pad[b * SSEQ + scol] ? -1e30f : 0.f;
        float sf[4];
        #pragma unroll
        for (int r = 0; r < 4; ++r) {
            const int trow = t0 + l4 * 4 + r;
            sf[r] = c[r] + amask[(size_t)trow * SSEQ + scol] + padd;
        }

        // tile row-max: 16-lane shfl reduce, then cross-wave via LDS
        float wm[4] = {sf[0], sf[1], sf[2], sf[3]};
        #pragma unroll
        for (int off = 1; off < 16; off <<= 1)
            #pragma unroll
            for (int r = 0; r < 4; ++r)
                wm[r] = fmaxf(wm[r], __shfl_xor(wm[r], off));
        if (l15 == 0)
            #pragma unroll
            for (int r = 0; r < 4; ++r)
                Mtile[w][l4 * 4 + r] = wm[r];
        __syncthreads();

        float sc_[4];
        #pragma unroll
        for (int r = 0; r < 4; ++r) {
            const int row = l4 * 4 + r;
            float tmax = fmaxf(fmaxf(Mtile[0][row], Mtile[1][row]),
                               fmaxf(Mtile[2][row], Mtile[3][row]));
            const float mnew = fmaxf(m_run[r], tmax);
            sc_[r] = __expf(m_run[r] - mnew);
            const float p = __expf(sf[r] - mnew);
            l_run[r] = l_run[r] * sc_[r] + p;
            m_run[r] = mnew;
            Ps[row][w * 16 + l15] = p;
        }
        if (w == 0 && l15 == 0)
            #pragma unroll
            for (int r = 0; r < 4; ++r)
                Sc[l4 * 4 + r] = sc_[r];
        __syncthreads();   // Ps + Sc visible

        // VALU PV (validated r6 mapping) with O rescale
        const float scv = Sc[prow];
        o[0] *= scv; o[1] *= scv; o[2] *= scv; o[3] *= scv;
        #pragma unroll
        for (int s4 = 0; s4 < 64; s4 += 4) {
            const float4 ps = *(const float4*)&Ps[prow][s4];
            const float4 v0 = *(const float4*)&Vs[s4 + 0][pd4];
            const float4 v1 = *(const float4*)&Vs[s4 + 1][pd4];
            const float4 v2 = *(const float4*)&Vs[s4 + 2][pd4];
            const float4 v3 = *(const float4*)&Vs[s4 + 3][pd4];
            o[0] += ps.x * v0.x + ps.y * v1.x + ps.z * v2.x + ps.w * v3.x;
            o[1] += ps.x * v0.y + ps.y * v1.y + ps.z * v2.y + ps.w * v3.y;
            o[2] += ps.x * v0.z + ps.y * v1.z + ps.z * v2.z + ps.w * v3.z;
            o[3] += ps.x * v0.w + ps.y * v1.w + ps.z * v2.w + ps.w * v3.w;
        }
    }

    // ---- merge L across lanes (m already consistent per row) ----
    #pragma unroll
    for (int off = 1; off < 16; off <<= 1)
        #pragma unroll
        for (int r = 0; r < 4; ++r)
            l_run[r] += __shfl_xor(l_run[r], off);
    __syncthreads();
    if (l15 == 0)
        #pragma unroll
        for (int r = 0; r < 4; ++r)
            Lred[w][l4 * 4 + r] = l_run[r];
    if (w == 0 && l15 == 0)
        #pragma unroll
        for (int r = 0; r < 4; ++r)
            Sc[l4 * 4 + r] = m_run[r];     // reuse Sc to publish m
    __syncthreads();
    if (tid < 16) {
        const float L = Lred[0][tid] + Lred[1][tid] + Lred[2][tid] + Lred[3][tid];
        Lfin[tid] = L;
        const size_t idx = ((size_t)(b * NH + h)) * TSEQ + t0 + tid;
        mfin_out[idx] = Sc[tid];
        lfin_out[idx] = L;
    }
    __syncthreads();

    const float invL = 1.0f / Lfin[prow];
    *(float4*)&attn_out[((size_t)((t0 + prow) * BATCH + b)) * EMBED + h * HD + pd4]
        = make_float4(o[0] * invL, o[1] * invL, o[2] * invL, o[3] * invL);
}

// ---------------------------------------------------------------------------
// Kernel B: avg_weights. Block = (b, 16 t-rows, 256-s chunk); grid 1024.
// Recomputes scores per head with the same validated hi/lo MFMA, applies
// exp(sf - m)/L using kernel A's (m,L), sums heads in registers, writes avg
// once (no RMW, no partials).
// ---------------------------------------------------------------------------
__global__ __launch_bounds__(256) void attn_avg(
    const float* __restrict__ qkv,
    const int* __restrict__ pad,
    const float* __restrict__ amask,
    const float* __restrict__ mfin,
    const float* __restrict__ lfin,
    float* __restrict__ avg)
{
    __shared__ __align__(16) unsigned short Kh[64 * 64];
    __shared__ __align__(16) unsigned short Kl[64 * 64];

    const int bid = blockIdx.x;
    const int sc4 = bid & 3;            // s-chunk 0..3 (256 wide)
    const int tb  = (bid >> 2) & 63;
    const int b   = bid >> 8;
    const int t0  = tb * 16;
    const int sbase = sc4 * 256;
    const int tid = threadIdx.x;
    const int w   = tid >> 6;
    const int l15 = tid & 15;
    const int l4  = (tid & 63) >> 4;

    const int ks_row = tid >> 2;
    const int ks_swz = 8 * (ks_row & 7);
    const int brow = w * 16 + l15;
    const int bswz = 8 * (brow & 7);

    // hoist amask + pad (head-independent)
    float am[4][4];
    float pv[4];
    #pragma unroll
    for (int st = 0; st < 4; ++st) {
        const int scol = sbase + st * 64 + w * 16 + l15;
        pv[st] = pad[b * SSEQ + scol] ? -1e30f : 0.f;
        #pragma unroll
        for (int r = 0; r < 4; ++r)
            am[st][r] = amask[(size_t)(t0 + l4 * 4 + r) * SSEQ + scol];
    }

    float acc[4][4] = {};   // [st][r]

    for (int h = 0; h < NH; ++h) {
        // Q frags hi/lo for this head
        short8 qh[2], ql[2];
        {
            const float* qrow = qkv + ((size_t)((t0 + l15) * BATCH + b)) * 3072 + h * HD;
            #pragma unroll
            for (int ks = 0; ks < 2; ++ks) {
                const float4 x0 = *(const float4*)(qrow + ks * 32 + l4 * 8);
                const float4 x1 = *(const float4*)(qrow + ks * 32 + l4 * 8 + 4);
                const float xf[8] = {x0.x, x0.y, x0.z, x0.w, x1.x, x1.y, x1.z, x1.w};
                short8 qhv, qlv;
                #pragma unroll
                for (int j = 0; j < 8; ++j) {
                    const unsigned short hi = f2bf(xf[j]);
                    qhv[j] = (short)hi;
                    qlv[j] = (short)f2bf(xf[j] - bf2f(hi));
                }
                qh[ks] = qhv; ql[ks] = qlv;
            }
        }
        // per-row m, 1/L for this head
        float mrow[4], invl[4];
        #pragma unroll
        for (int r = 0; r < 4; ++r) {
            const size_t idx = ((size_t)(b * NH + h)) * TSEQ + t0 + l4 * 4 + r;
            mrow[r] = mfin[idx];
            invl[r] = 1.0f / lfin[idx];
        }

        #pragma unroll
        for (int st = 0; st < 4; ++st) {
            const int s0 = sbase + st * 64;
            __syncthreads();
            {   // stage K hi/lo (validated)
                const float* krow = qkv + ((size_t)((s0 + ks_row) * BATCH + b)) * 3072
                                  + EMBED + h * HD;
                #pragma unroll
                for (int it = 0; it < 4; ++it) {
                    const int d = (tid & 3) * 4 + it * 16;
                    const float4 x = *(const float4*)(krow + d);
                    const float xf[4] = {x.x, x.y, x.z, x.w};
                    ushort4v uh, ul;
                    #pragma unroll
                    for (int j = 0; j < 4; ++j) {
                        const unsigned short hi = f2bf(xf[j]);
                        uh[j] = hi;
                        ul[j] = f2bf(xf[j] - bf2f(hi));
                    }
                    *(ushort4v*)&Kh[ks_row * 64 + (d ^ ks_swz)] = uh;
                    *(ushort4v*)&Kl[ks_row * 64 + (d ^ ks_swz)] = ul;
                }
            }
            __syncthreads();

            const short8 kh0 = *(const short8*)&Kh[brow * 64 + ((l4 * 8) ^ bswz)];
            const short8 kh1 = *(const short8*)&Kh[brow * 64 + ((32 + l4 * 8) ^ bswz)];
            const short8 kl0 = *(const short8*)&Kl[brow * 64 + ((l4 * 8) ^ bswz)];
            const short8 kl1 = *(const short8*)&Kl[brow * 64 + ((32 + l4 * 8) ^ bswz)];
            float4v c = {0.f, 0.f, 0.f, 0.f};
            c = __builtin_amdgcn_mfma_f32_16x16x32_bf16(qh[0], kh0, c, 0, 0, 0);
            c = __builtin_amdgcn_mfma_f32_16x16x32_bf16(qh[1], kh1, c, 0, 0, 0);
            c = __builtin_amdgcn_mfma_f32_16x16x32_bf16(ql[0], kh0, c, 0, 0, 0);
            c = __builtin_amdgcn_mfma_f32_16x16x32_bf16(ql[1], kh1, c, 0, 0, 0);
            c = __builtin_amdgcn_mfma_f32_16x16x32_bf16(qh[0], kl0, c, 0, 0, 0);
            c = __builtin_amdgcn_mfma_f32_16x16x32_bf16(qh[1], kl1, c, 0, 0, 0);

            #pragma unroll
            for (int r = 0; r < 4; ++r) {
                const float sf = c[r] + am[st][r] + pv[st];
                acc[st][r] += __expf(sf - mrow[r]) * invl[r];
            }
        }
    }

    const float inv_H = 1.0f / NH;
    #pragma unroll
    for (int st = 0; st < 4; ++st) {
        const int scol = sbase + st * 64 + w * 16 + l15;
        #pragma unroll
        for (int r = 0; r < 4; ++r)
            avg[((size_t)(b * TSEQ + t0 + l4 * 4 + r)) * SSEQ + scol]
                = acc[st][r] * inv_H;
    }
}

// ---------------------------------------------------------------------------
extern "C" void kernel_launch(void* const* d_in, const int* in_sizes, int n_in,
                              void* d_out, int out_size, void* d_ws, size_t ws_size,
                              hipStream_t stream) {
    const float* query = (const float*)d_in[0];
    const float* key   = (const float*)d_in[1];
    const float* value = (const float*)d_in[2];
    const int*   pad   = (const int*)d_in[3];
    const float* amask = (const float*)d_in[4];
    const float* wqkv  = (const float*)d_in[5];
    const float* bqkv  = (const float*)d_in[6];
    const float* wout  = (const float*)d_in[7];
    const float* bout  = (const float*)d_in[8];

    float* out = (float*)d_out;
    float* avg = out + (size_t)TSEQ * BATCH * EMBED;

    float* qkv   = (float*)d_ws;                                  // 48 MB
    float* attn  = qkv + (size_t)(TSEQ * BATCH) * (3 * EMBED);    // 16 MB
    float* mfin  = attn + (size_t)(TSEQ * BATCH) * EMBED;         // 256 KB
    float* lfin  = mfin + (size_t)BATCH * NH * TSEQ;              // 256 KB

    const int M = TSEQ * BATCH;
    const float scaling = 0.125f;

    dim3 g1(3 * EMBED / 128, M / 128);
    gemm_nt<<<g1, 256, 0, stream>>>(query, key, value, wqkv, bqkv, qkv,
                                    M, 3 * EMBED, EMBED, EMBED, scaling);

    attn_flash<<<dim3(4096), 256, 0, stream>>>(qkv, pad, amask, attn, mfin, lfin);

    attn_avg<<<dim3(1024), 256, 0, stream>>>(qkv, pad, amask, mfin, lfin, avg);

    dim3 g3(EMBED / 128, M / 128);
    gemm_nt<<<g3, 256, 0, stream>>>(attn, attn, attn, wout, bout, out,
                                    M, EMBED, EMBED, 0, 1.f);
}

// Round 8
// 1029.135 us; speedup vs baseline: 1.3657x; 1.2336x over previous
//
#include <hip/hip_runtime.h>
#include <hip/hip_bf16.h>

#define EMBED 1024
#define NH 16
#define HD 64
#define TSEQ 1024
#define SSEQ 1024
#define BATCH 4

using short8   = __attribute__((ext_vector_type(8))) short;
using float4v  = __attribute__((ext_vector_type(4))) float;
using ushort4v = __attribute__((ext_vector_type(4))) unsigned short;

__device__ __forceinline__ unsigned short f2bf(float f) {
    union { float f; unsigned int u; } v; v.f = f;
    unsigned int r = v.u + 0x7fffu + ((v.u >> 16) & 1u);   // RNE
    return (unsigned short)(r >> 16);
}
__device__ __forceinline__ float bf2f(unsigned short u) {
    union { unsigned int u; float f; } v; v.u = ((unsigned int)u) << 16;
    return v.f;
}

// ---------------------------------------------------------------------------
// QKV GEMM (validated fp32 core) + pack epilogue:
//   q cols -> Qhi/Qlo bf16 [b*16+h][t][d], scaled by 0.125
//   k cols -> Khi/Klo bf16 [b*16+h][s][d]
//   v cols -> fp32 Vbuf[m][1024] (repacked to Vt by repack_vt)
// M=4096, N=3072, K=1024 hardcoded.
// ---------------------------------------------------------------------------
__global__ __launch_bounds__(256) void gemm_qkv(
    const float* __restrict__ A0, const float* __restrict__ A1,
    const float* __restrict__ A2,
    const float* __restrict__ W, const float* __restrict__ bias,
    unsigned short* __restrict__ Qhi, unsigned short* __restrict__ Qlo,
    unsigned short* __restrict__ Khi, unsigned short* __restrict__ Klo,
    float* __restrict__ Vbuf)
{
    __shared__ float As[16][128 + 4];
    __shared__ float Bs[16][128 + 4];

    const int m0 = blockIdx.y * 128;
    const int n0 = blockIdx.x * 128;
    const float* A = (n0 < 1024) ? A0 : (n0 < 2048 ? A1 : A2);

    const int tid = threadIdx.x;
    const int ty = tid >> 4;
    const int tx = tid & 15;
    const int lr = tid >> 1;
    const int lk = (tid & 1) * 8;

    const float* Ap = A + (size_t)(m0 + lr) * 1024 + lk;
    const float* Wp = W + (size_t)(n0 + lr) * 1024 + lk;

    float acc[8][8] = {};

    for (int k0 = 0; k0 < 1024; k0 += 16) {
        const float4 a0 = *(const float4*)(Ap + k0);
        const float4 a1 = *(const float4*)(Ap + k0 + 4);
        const float4 b0 = *(const float4*)(Wp + k0);
        const float4 b1 = *(const float4*)(Wp + k0 + 4);
        __syncthreads();
        As[lk + 0][lr] = a0.x; As[lk + 1][lr] = a0.y;
        As[lk + 2][lr] = a0.z; As[lk + 3][lr] = a0.w;
        As[lk + 4][lr] = a1.x; As[lk + 5][lr] = a1.y;
        As[lk + 6][lr] = a1.z; As[lk + 7][lr] = a1.w;
        Bs[lk + 0][lr] = b0.x; Bs[lk + 1][lr] = b0.y;
        Bs[lk + 2][lr] = b0.z; Bs[lk + 3][lr] = b0.w;
        Bs[lk + 4][lr] = b1.x; Bs[lk + 5][lr] = b1.y;
        Bs[lk + 6][lr] = b1.z; Bs[lk + 7][lr] = b1.w;
        __syncthreads();

        #pragma unroll
        for (int kk = 0; kk < 16; ++kk) {
            const float4 av0 = *(const float4*)&As[kk][ty * 4];
            const float4 av1 = *(const float4*)&As[kk][64 + ty * 4];
            const float4 bv0 = *(const float4*)&Bs[kk][tx * 4];
            const float4 bv1 = *(const float4*)&Bs[kk][64 + tx * 4];
            const float ar[8] = {av0.x, av0.y, av0.z, av0.w,
                                 av1.x, av1.y, av1.z, av1.w};
            const float br[8] = {bv0.x, bv0.y, bv0.z, bv0.w,
                                 bv1.x, bv1.y, bv1.z, bv1.w};
            #pragma unroll
            for (int i = 0; i < 8; ++i)
                #pragma unroll
                for (int j = 0; j < 8; ++j)
                    acc[i][j] += ar[i] * br[j];
        }
    }

    const int nregion = n0 >> 10;   // 0=q, 1=k, 2=v (uniform per block)
    #pragma unroll
    for (int ih = 0; ih < 2; ++ih) {
        #pragma unroll
        for (int i = 0; i < 4; ++i) {
            const int m = m0 + ih * 64 + ty * 4 + i;
            const int t = m >> 2;       // sequence position
            const int bb = m & 3;       // batch
            #pragma unroll
            for (int jh = 0; jh < 2; ++jh) {
                const int n = n0 + jh * 64 + tx * 4;
                float v[4];
                #pragma unroll
                for (int j = 0; j < 4; ++j)
                    v[j] = acc[ih * 4 + i][jh * 4 + j] + bias[n + j];

                if (nregion == 0) {
                    ushort4v hq, lq;
                    #pragma unroll
                    for (int j = 0; j < 4; ++j) {
                        const float x = v[j] * 0.125f;
                        const unsigned short hi = f2bf(x);
                        hq[j] = hi;
                        lq[j] = f2bf(x - bf2f(hi));
                    }
                    const int hh = n >> 6, dd = n & 63;
                    const size_t idx = ((size_t)(bb * 16 + hh) << 16)
                                     + (size_t)t * 64 + dd;
                    *(ushort4v*)(Qhi + idx) = hq;
                    *(ushort4v*)(Qlo + idx) = lq;
                } else if (nregion == 1) {
                    ushort4v hq, lq;
                    #pragma unroll
                    for (int j = 0; j < 4; ++j) {
                        const unsigned short hi = f2bf(v[j]);
                        hq[j] = hi;
                        lq[j] = f2bf(v[j] - bf2f(hi));
                    }
                    const int nn = n - 1024;
                    const int hh = nn >> 6, dd = nn & 63;
                    const size_t idx = ((size_t)(bb * 16 + hh) << 16)
                                     + (size_t)t * 64 + dd;
                    *(ushort4v*)(Khi + idx) = hq;
                    *(ushort4v*)(Klo + idx) = lq;
                } else {
                    *(float4*)&Vbuf[(size_t)m * 1024 + (n - 2048)]
                        = make_float4(v[0], v[1], v[2], v[3]);
                }
            }
        }
    }
}

// ---------------------------------------------------------------------------
// Repack fp32 v [m=(s,b)][h*64+d] -> Vthi/Vtlo bf16 [b*16+h][d][s]
// ---------------------------------------------------------------------------
__global__ __launch_bounds__(256) void repack_vt(
    const float* __restrict__ vbuf,
    unsigned short* __restrict__ Vthi, unsigned short* __restrict__ Vtlo)
{
    __shared__ float T[64][65];
    const int bh = blockIdx.x >> 4;
    const int s0 = (blockIdx.x & 15) * 64;
    const int b = bh >> 4, hh = bh & 15;
    const int tid = threadIdx.x;

    #pragma unroll
    for (int i = 0; i < 4; ++i) {
        const int s = (tid >> 4) + i * 16;
        const int d = (tid & 15) * 4;
        const float4 x = *(const float4*)&vbuf[(size_t)((s0 + s) * 4 + b) * 1024
                                               + hh * 64 + d];
        T[s][d] = x.x; T[s][d + 1] = x.y; T[s][d + 2] = x.z; T[s][d + 3] = x.w;
    }
    __syncthreads();

    const int d = tid >> 2;
    const int sg = (tid & 3) * 16;
    ushort4v hv[4], lv[4];
    #pragma unroll
    for (int k = 0; k < 16; ++k) {
        const float x = T[sg + k][d];
        const unsigned short hi = f2bf(x);
        hv[k >> 2][k & 3] = hi;
        lv[k >> 2][k & 3] = f2bf(x - bf2f(hi));
    }
    const size_t o = ((size_t)bh << 16) + (size_t)d * 1024 + s0 + sg;
    #pragma unroll
    for (int q = 0; q < 4; ++q) {
        *(ushort4v*)(Vthi + o + q * 4) = hv[q];
        *(ushort4v*)(Vtlo + o + q * 4) = lv[q];
    }
}

// ---------------------------------------------------------------------------
// Flash attention, barrier-free main loop. Block=(b,h,64 t-rows), 4 waves;
// wave w owns t-rows tw..tw+15 and ALL s (swapped QK^T: mfma(K,Q) -> lane
// holds scores for s-local=l4*4+r(+sub*16), t=l15 -> softmax lane-local +
// 2 quad-shfls). P transposed to PV A-frags via per-wave 2KB swizzled LDS
// strip (own-wave: lgkmcnt(0)+sched_barrier, no s_barrier). PV = P(hi/lo) x
// V(hi/lo) 3-term MFMA. Per-row (m,L) stored for the avg kernel.
// ---------------------------------------------------------------------------
__global__ __launch_bounds__(256) void attn_flash2(
    const unsigned short* __restrict__ Qhi, const unsigned short* __restrict__ Qlo,
    const unsigned short* __restrict__ Khi, const unsigned short* __restrict__ Klo,
    const unsigned short* __restrict__ Vthi, const unsigned short* __restrict__ Vtlo,
    const int* __restrict__ pad, const float* __restrict__ amask,
    float* __restrict__ attn_out,
    float* __restrict__ mfin, float* __restrict__ lfin)
{
    __shared__ __align__(16) unsigned short Ph[4][16 * 64];
    __shared__ __align__(16) unsigned short Pl[4][16 * 64];

    const int bid = blockIdx.x;
    const int tblk = bid & 15;
    const int h   = (bid >> 4) & 15;
    const int b   = bid >> 8;
    const int bh  = b * 16 + h;
    const int tid = threadIdx.x;
    const int w   = tid >> 6;
    const int l15 = tid & 15;
    const int l4  = (tid & 63) >> 4;
    const int tw  = tblk * 64 + w * 16;

    short8 qhf[2], qlf[2];
    {
        const size_t qb = ((size_t)bh << 16) + (size_t)(tw + l15) * 64 + l4 * 8;
        qhf[0] = *(const short8*)(Qhi + qb);
        qhf[1] = *(const short8*)(Qhi + qb + 32);
        qlf[0] = *(const short8*)(Qlo + qb);
        qlf[1] = *(const short8*)(Qlo + qb + 32);
    }

    float m_run = -1e30f, l_run = 0.f;
    float4v oc[4] = {{0,0,0,0},{0,0,0,0},{0,0,0,0},{0,0,0,0}};
    unsigned short* ph = Ph[w];
    unsigned short* pl = Pl[w];
    const int swz = (l15 & 7) << 3;

    for (int st = 0; st < 16; ++st) {
        const int s0 = st * 64;

        // ---- QK^T (swapped: A=K rows=s, B=Q cols=t) ----
        float4v c[4];
        #pragma unroll
        for (int sub = 0; sub < 4; ++sub) {
            const size_t kb = ((size_t)bh << 16)
                            + (size_t)(s0 + sub * 16 + l15) * 64 + l4 * 8;
            const short8 kh0 = *(const short8*)(Khi + kb);
            const short8 kh1 = *(const short8*)(Khi + kb + 32);
            const short8 kl0 = *(const short8*)(Klo + kb);
            const short8 kl1 = *(const short8*)(Klo + kb + 32);
            float4v cc = {0.f, 0.f, 0.f, 0.f};
            cc = __builtin_amdgcn_mfma_f32_16x16x32_bf16(kh0, qhf[0], cc, 0, 0, 0);
            cc = __builtin_amdgcn_mfma_f32_16x16x32_bf16(kh1, qhf[1], cc, 0, 0, 0);
            cc = __builtin_amdgcn_mfma_f32_16x16x32_bf16(kl0, qhf[0], cc, 0, 0, 0);
            cc = __builtin_amdgcn_mfma_f32_16x16x32_bf16(kl1, qhf[1], cc, 0, 0, 0);
            cc = __builtin_amdgcn_mfma_f32_16x16x32_bf16(kh0, qlf[0], cc, 0, 0, 0);
            cc = __builtin_amdgcn_mfma_f32_16x16x32_bf16(kh1, qlf[1], cc, 0, 0, 0);
            c[sub] = cc;
        }

        // ---- masks + tile max (lane-local + quad merge) ----
        float p[4][4];
        float tmax = -1e30f;
        #pragma unroll
        for (int sub = 0; sub < 4; ++sub) {
            const int sbase = s0 + sub * 16 + l4 * 4;
            const float4 am = *(const float4*)(amask + (size_t)(tw + l15) * SSEQ + sbase);
            const int4  pd = *(const int4*)(pad + b * SSEQ + sbase);
            const float amr[4] = {am.x, am.y, am.z, am.w};
            const int   pdr[4] = {pd.x, pd.y, pd.z, pd.w};
            #pragma unroll
            for (int r = 0; r < 4; ++r) {
                const float sf = c[sub][r] + amr[r] + (pdr[r] ? -1e30f : 0.f);
                p[sub][r] = sf;
                tmax = fmaxf(tmax, sf);
            }
        }
        tmax = fmaxf(tmax, __shfl_xor(tmax, 16));
        tmax = fmaxf(tmax, __shfl_xor(tmax, 32));
        const float mnew = fmaxf(m_run, tmax);
        const float sc = __expf(m_run - mnew);
        m_run = mnew;

        float lsum = 0.f;
        #pragma unroll
        for (int sub = 0; sub < 4; ++sub)
            #pragma unroll
            for (int r = 0; r < 4; ++r) {
                const float pv = __expf(p[sub][r] - mnew);
                p[sub][r] = pv;
                lsum += pv;
            }
        l_run = l_run * sc + lsum;

        // ---- P -> bf16 hi/lo strips (own-wave LDS, swizzled) ----
        #pragma unroll
        for (int sub = 0; sub < 4; ++sub) {
            ushort4v hq, lq;
            #pragma unroll
            for (int r = 0; r < 4; ++r) {
                const unsigned short hi = f2bf(p[sub][r]);
                hq[r] = hi;
                lq[r] = f2bf(p[sub][r] - bf2f(hi));
            }
            const int col = (sub * 16 + l4 * 4) ^ swz;
            *(ushort4v*)&ph[l15 * 64 + col] = hq;
            *(ushort4v*)&pl[l15 * 64 + col] = lq;
        }
        asm volatile("s_waitcnt lgkmcnt(0)" ::: "memory");
        __builtin_amdgcn_sched_barrier(0);

        short8 pah[2], pal[2];
        #pragma unroll
        for (int kh = 0; kh < 2; ++kh) {
            const int col = (kh * 32 + l4 * 8) ^ swz;
            pah[kh] = *(const short8*)&ph[l15 * 64 + col];
            pal[kh] = *(const short8*)&pl[l15 * 64 + col];
        }

        // ---- O rescale (sc redistributed to row layout) ----
        float scr[4];
        #pragma unroll
        for (int r = 0; r < 4; ++r) scr[r] = __shfl(sc, l4 * 4 + r);
        #pragma unroll
        for (int ds = 0; ds < 4; ++ds)
            #pragma unroll
            for (int r = 0; r < 4; ++r)
                oc[ds][r] *= scr[r];

        // ---- PV: 3-term (PhVh + PlVh + PhVl) ----
        #pragma unroll
        for (int ds = 0; ds < 4; ++ds) {
            const size_t vb = ((size_t)bh << 16)
                            + (size_t)(ds * 16 + l15) * 1024 + s0 + l4 * 8;
            const short8 vh0 = *(const short8*)(Vthi + vb);
            const short8 vh1 = *(const short8*)(Vthi + vb + 32);
            const short8 vl0 = *(const short8*)(Vtlo + vb);
            const short8 vl1 = *(const short8*)(Vtlo + vb + 32);
            float4v t = oc[ds];
            t = __builtin_amdgcn_mfma_f32_16x16x32_bf16(pah[0], vh0, t, 0, 0, 0);
            t = __builtin_amdgcn_mfma_f32_16x16x32_bf16(pah[1], vh1, t, 0, 0, 0);
            t = __builtin_amdgcn_mfma_f32_16x16x32_bf16(pal[0], vh0, t, 0, 0, 0);
            t = __builtin_amdgcn_mfma_f32_16x16x32_bf16(pal[1], vh1, t, 0, 0, 0);
            t = __builtin_amdgcn_mfma_f32_16x16x32_bf16(pah[0], vl0, t, 0, 0, 0);
            t = __builtin_amdgcn_mfma_f32_16x16x32_bf16(pah[1], vl1, t, 0, 0, 0);
            oc[ds] = t;
        }
    }

    // ---- final merges + stores ----
    l_run += __shfl_xor(l_run, 16);
    l_run += __shfl_xor(l_run, 32);
    if (l4 == 0) {
        mfin[bh * 1024 + tw + l15] = m_run;
        lfin[bh * 1024 + tw + l15] = l_run;
    }
    float invL[4];
    #pragma unroll
    for (int r = 0; r < 4; ++r) invL[r] = 1.0f / __shfl(l_run, l4 * 4 + r);

    #pragma unroll
    for (int ds = 0; ds < 4; ++ds)
        #pragma unroll
        for (int r = 0; r < 4; ++r) {
            const int t = tw + l4 * 4 + r;
            attn_out[(size_t)(t * 4 + b) * 1024 + h * 64 + ds * 16 + l15]
                = oc[ds][r] * invL[r];
        }
}

// ---------------------------------------------------------------------------
// avg_weights: block=(b,16 t-rows, 256-s chunk); wave w owns a 64-s strip.
// Recomputes scores from packs (swapped MFMA), p=exp(sf-m)/L, sums heads
// in registers, writes once. No LDS, no barriers.
// ---------------------------------------------------------------------------
__global__ __launch_bounds__(256) void attn_avg2(
    const unsigned short* __restrict__ Qhi, const unsigned short* __restrict__ Qlo,
    const unsigned short* __restrict__ Khi, const unsigned short* __restrict__ Klo,
    const int* __restrict__ pad, const float* __restrict__ amask,
    const float* __restrict__ mfin, const float* __restrict__ lfin,
    float* __restrict__ avg)
{
    const int bid = blockIdx.x;
    const int sq = bid & 3;
    const int tt = (bid >> 2) & 63;
    const int b  = bid >> 8;
    const int t0 = tt * 16;
    const int tid = threadIdx.x;
    const int w   = tid >> 6;
    const int l15 = tid & 15;
    const int l4  = (tid & 63) >> 4;
    const int sw0 = sq * 256 + w * 64;

    float amr[4][4];
    #pragma unroll
    for (int sub = 0; sub < 4; ++sub) {
        const int sbase = sw0 + sub * 16 + l4 * 4;
        const float4 am = *(const float4*)(amask + (size_t)(t0 + l15) * SSEQ + sbase);
        const int4  pd = *(const int4*)(pad + b * SSEQ + sbase);
        amr[sub][0] = am.x + (pd.x ? -1e30f : 0.f);
        amr[sub][1] = am.y + (pd.y ? -1e30f : 0.f);
        amr[sub][2] = am.z + (pd.z ? -1e30f : 0.f);
        amr[sub][3] = am.w + (pd.w ? -1e30f : 0.f);
    }

    float acc[4][4] = {};

    for (int hh = 0; hh < NH; ++hh) {
        const int bh = b * 16 + hh;
        short8 qhf[2], qlf[2];
        {
            const size_t qb = ((size_t)bh << 16) + (size_t)(t0 + l15) * 64 + l4 * 8;
            qhf[0] = *(const short8*)(Qhi + qb);
            qhf[1] = *(const short8*)(Qhi + qb + 32);
            qlf[0] = *(const short8*)(Qlo + qb);
            qlf[1] = *(const short8*)(Qlo + qb + 32);
        }
        const float m  = mfin[bh * 1024 + t0 + l15];
        const float il = 1.0f / lfin[bh * 1024 + t0 + l15];

        #pragma unroll
        for (int sub = 0; sub < 4; ++sub) {
            const size_t kb = ((size_t)bh << 16)
                            + (size_t)(sw0 + sub * 16 + l15) * 64 + l4 * 8;
            const short8 kh0 = *(const short8*)(Khi + kb);
            const short8 kh1 = *(const short8*)(Khi + kb + 32);
            const short8 kl0 = *(const short8*)(Klo + kb);
            const short8 kl1 = *(const short8*)(Klo + kb + 32);
            float4v cc = {0.f, 0.f, 0.f, 0.f};
            cc = __builtin_amdgcn_mfma_f32_16x16x32_bf16(kh0, qhf[0], cc, 0, 0, 0);
            cc = __builtin_amdgcn_mfma_f32_16x16x32_bf16(kh1, qhf[1], cc, 0, 0, 0);
            cc = __builtin_amdgcn_mfma_f32_16x16x32_bf16(kl0, qhf[0], cc, 0, 0, 0);
            cc = __builtin_amdgcn_mfma_f32_16x16x32_bf16(kl1, qhf[1], cc, 0, 0, 0);
            cc = __builtin_amdgcn_mfma_f32_16x16x32_bf16(kh0, qlf[0], cc, 0, 0, 0);
            cc = __builtin_amdgcn_mfma_f32_16x16x32_bf16(kh1, qlf[1], cc, 0, 0, 0);
            #pragma unroll
            for (int r = 0; r < 4; ++r)
                acc[sub][r] += __expf(cc[r] + amr[sub][r] - m) * il;
        }
    }

    const float ivH = 1.0f / NH;
    #pragma unroll
    for (int sub = 0; sub < 4; ++sub) {
        float4 o;
        o.x = acc[sub][0] * ivH; o.y = acc[sub][1] * ivH;
        o.z = acc[sub][2] * ivH; o.w = acc[sub][3] * ivH;
        *(float4*)&avg[(size_t)(b * 1024 + t0 + l15) * 1024
                       + sw0 + sub * 16 + l4 * 4] = o;
    }
}

// ---------------------------------------------------------------------------
// Out-proj NT GEMM (validated r3 version, fp32)
// ---------------------------------------------------------------------------
__global__ __launch_bounds__(256) void gemm_nt(
    const float* __restrict__ A0, const float* __restrict__ W,
    const float* __restrict__ bias, float* __restrict__ C, int M, int N, int K)
{
    __shared__ float As[16][128 + 4];
    __shared__ float Bs[16][128 + 4];

    const int m0 = blockIdx.y * 128;
    const int n0 = blockIdx.x * 128;
    const int tid = threadIdx.x;
    const int ty = tid >> 4;
    const int tx = tid & 15;
    const int lr = tid >> 1;
    const int lk = (tid & 1) * 8;

    const float* Ap = A0 + (size_t)(m0 + lr) * K + lk;
    const float* Wp = W + (size_t)(n0 + lr) * K + lk;

    float acc[8][8] = {};

    for (int k0 = 0; k0 < K; k0 += 16) {
        const float4 a0 = *(const float4*)(Ap + k0);
        const float4 a1 = *(const float4*)(Ap + k0 + 4);
        const float4 b0 = *(const float4*)(Wp + k0);
        const float4 b1 = *(const float4*)(Wp + k0 + 4);
        __syncthreads();
        As[lk + 0][lr] = a0.x; As[lk + 1][lr] = a0.y;
        As[lk + 2][lr] = a0.z; As[lk + 3][lr] = a0.w;
        As[lk + 4][lr] = a1.x; As[lk + 5][lr] = a1.y;
        As[lk + 6][lr] = a1.z; As[lk + 7][lr] = a1.w;
        Bs[lk + 0][lr] = b0.x; Bs[lk + 1][lr] = b0.y;
        Bs[lk + 2][lr] = b0.z; Bs[lk + 3][lr] = b0.w;
        Bs[lk + 4][lr] = b1.x; Bs[lk + 5][lr] = b1.y;
        Bs[lk + 6][lr] = b1.z; Bs[lk + 7][lr] = b1.w;
        __syncthreads();

        #pragma unroll
        for (int kk = 0; kk < 16; ++kk) {
            const float4 av0 = *(const float4*)&As[kk][ty * 4];
            const float4 av1 = *(const float4*)&As[kk][64 + ty * 4];
            const float4 bv0 = *(const float4*)&Bs[kk][tx * 4];
            const float4 bv1 = *(const float4*)&Bs[kk][64 + tx * 4];
            const float ar[8] = {av0.x, av0.y, av0.z, av0.w,
                                 av1.x, av1.y, av1.z, av1.w};
            const float br[8] = {bv0.x, bv0.y, bv0.z, bv0.w,
                                 bv1.x, bv1.y, bv1.z, bv1.w};
            #pragma unroll
            for (int i = 0; i < 8; ++i)
                #pragma unroll
                for (int j = 0; j < 8; ++j)
                    acc[i][j] += ar[i] * br[j];
        }
    }

    #pragma unroll
    for (int ih = 0; ih < 2; ++ih) {
        #pragma unroll
        for (int i = 0; i < 4; ++i) {
            const int m = m0 + ih * 64 + ty * 4 + i;
            #pragma unroll
            for (int jh = 0; jh < 2; ++jh) {
                const int n = n0 + jh * 64 + tx * 4;
                float4 r;
                r.x = acc[ih * 4 + i][jh * 4 + 0] + bias[n + 0];
                r.y = acc[ih * 4 + i][jh * 4 + 1] + bias[n + 1];
                r.z = acc[ih * 4 + i][jh * 4 + 2] + bias[n + 2];
                r.w = acc[ih * 4 + i][jh * 4 + 3] + bias[n + 3];
                *(float4*)&C[(size_t)m * N + n] = r;
            }
        }
    }
}

// ---------------------------------------------------------------------------
extern "C" void kernel_launch(void* const* d_in, const int* in_sizes, int n_in,
                              void* d_out, int out_size, void* d_ws, size_t ws_size,
                              hipStream_t stream) {
    const float* query = (const float*)d_in[0];
    const float* key   = (const float*)d_in[1];
    const float* value = (const float*)d_in[2];
    const int*   pad   = (const int*)d_in[3];
    const float* amask = (const float*)d_in[4];
    const float* wqkv  = (const float*)d_in[5];
    const float* bqkv  = (const float*)d_in[6];
    const float* wout  = (const float*)d_in[7];
    const float* bout  = (const float*)d_in[8];

    float* out = (float*)d_out;
    float* avg = out + (size_t)TSEQ * BATCH * EMBED;

    // ws layout (67,633,152 B total == proven r7 budget):
    //   [0, 16.78MB)  vbuf fp32 (later ALIASED as attn_out: repack reads it
    //                 before attn_flash2 writes it; stream-ordered)
    //   6 bf16 packs of 8.39MB: Qhi,Qlo,Khi,Klo,Vthi,Vtlo
    //   mfin, lfin: 256KB each
    float* vbuf = (float*)d_ws;
    unsigned short* Qhi  = (unsigned short*)(vbuf + 4194304);
    unsigned short* Qlo  = Qhi + 4194304;
    unsigned short* Khi  = Qlo + 4194304;
    unsigned short* Klo  = Khi + 4194304;
    unsigned short* Vthi = Klo + 4194304;
    unsigned short* Vtlo = Vthi + 4194304;
    float* mfin = (float*)(Vtlo + 4194304);
    float* lfin = mfin + 65536;
    float* attn = vbuf;   // alias, safe (see above)

    gemm_qkv<<<dim3(24, 32), 256, 0, stream>>>(query, key, value, wqkv, bqkv,
                                               Qhi, Qlo, Khi, Klo, vbuf);

    repack_vt<<<dim3(1024), 256, 0, stream>>>(vbuf, Vthi, Vtlo);

    attn_flash2<<<dim3(1024), 256, 0, stream>>>(Qhi, Qlo, Khi, Klo, Vthi, Vtlo,
                                                pad, amask, attn, mfin, lfin);

    attn_avg2<<<dim3(1024), 256, 0, stream>>>(Qhi, Qlo, Khi, Klo, pad, amask,
                                              mfin, lfin, avg);

    gemm_nt<<<dim3(8, 32), 256, 0, stream>>>(attn, wout, bout, out,
                                             4096, 1024, 1024);
}

// Round 9
// 813.012 us; speedup vs baseline: 1.7287x; 1.2658x over previous
//
#include <hip/hip_runtime.h>
#include <hip/hip_bf16.h>

#define EMBED 1024
#define NH 16
#define HD 64
#define TSEQ 1024
#define SSEQ 1024
#define BATCH 4

using short8   = __attribute__((ext_vector_type(8))) short;
using float4v  = __attribute__((ext_vector_type(4))) float;
using ushort4v = __attribute__((ext_vector_type(4))) unsigned short;

__device__ __forceinline__ unsigned short f2bf(float f) {
    union { float f; unsigned int u; } v; v.f = f;
    unsigned int r = v.u + 0x7fffu + ((v.u >> 16) & 1u);   // RNE
    return (unsigned short)(r >> 16);
}
__device__ __forceinline__ float bf2f(unsigned short u) {
    union { unsigned int u; float f; } v; v.u = ((unsigned int)u) << 16;
    return v.f;
}

// ---------------------------------------------------------------------------
// Elementwise fp32 -> bf16 hi/lo packs (for weight matrices)
// ---------------------------------------------------------------------------
__global__ __launch_bounds__(256) void conv_hilo(
    const float* __restrict__ src,
    unsigned short* __restrict__ hi, unsigned short* __restrict__ lo, int n4)
{
    const int i = blockIdx.x * 256 + threadIdx.x;
    if (i >= n4) return;
    const float4 x = ((const float4*)src)[i];
    const float xf[4] = {x.x, x.y, x.z, x.w};
    ushort4v h, l;
    #pragma unroll
    for (int j = 0; j < 4; ++j) {
        const unsigned short hb = f2bf(xf[j]);
        h[j] = hb;
        l[j] = f2bf(xf[j] - bf2f(hb));
    }
    ((ushort4v*)hi)[i] = h;
    ((ushort4v*)lo)[i] = l;
}

// ---------------------------------------------------------------------------
// Barrier-free MFMA NT GEMM: C[m,n] = sum_k A[m,k]*W[n,k] + bias[n].
// A fp32 (converted to hi/lo bf16 in-register at load); W pre-packed hi/lo.
// 3-term hi/lo product -> ~fp32-accurate results (residual ~2^-16 rel).
// Block 256 thr = 4 waves in 2x2; wave tile 64x64 = 16 MFMA C-tiles.
// No LDS, no __syncthreads. mode 0: QKV pack epilogue (validated r8 logic);
// mode 1: plain fp32 C store.
// ---------------------------------------------------------------------------
__global__ __launch_bounds__(256) void gemm_mfma(
    const float* __restrict__ A0, const float* __restrict__ A1,
    const float* __restrict__ A2,
    const unsigned short* __restrict__ Wh, const unsigned short* __restrict__ Wl,
    const float* __restrict__ bias, int mode,
    unsigned short* __restrict__ Qhi, unsigned short* __restrict__ Qlo,
    unsigned short* __restrict__ Khi, unsigned short* __restrict__ Klo,
    float* __restrict__ Vbuf, float* __restrict__ Cout)
{
    const int m0 = blockIdx.y * 128;
    const int n0 = blockIdx.x * 128;
    const float* A = (n0 < 1024) ? A0 : (n0 < 2048 ? A1 : A2);

    const int tid = threadIdx.x;
    const int w   = tid >> 6;
    const int l15 = tid & 15;
    const int l4  = (tid & 63) >> 4;
    const int wm  = (w >> 1) * 64;   // wave m-offset
    const int wn  = (w & 1) * 64;    // wave n-offset

    float4v acc[4][4] = {};

    const size_t a_base = (size_t)(m0 + wm + l15) * 1024 + l4 * 8;
    const size_t w_base = (size_t)(n0 + wn + l15) * 1024 + l4 * 8;

    for (int k0 = 0; k0 < 1024; k0 += 32) {
        // A-frags: fp32 -> hi/lo bf16 in-register
        short8 ah[4], al[4];
        #pragma unroll
        for (int mt = 0; mt < 4; ++mt) {
            const float* ap = A + a_base + (size_t)mt * 16 * 1024 + k0;
            const float4 x0 = *(const float4*)ap;
            const float4 x1 = *(const float4*)(ap + 4);
            const float xf[8] = {x0.x, x0.y, x0.z, x0.w, x1.x, x1.y, x1.z, x1.w};
            short8 hv, lv;
            #pragma unroll
            for (int j = 0; j < 8; ++j) {
                const unsigned short hb = f2bf(xf[j]);
                hv[j] = (short)hb;
                lv[j] = (short)f2bf(xf[j] - bf2f(hb));
            }
            ah[mt] = hv; al[mt] = lv;
        }
        // B-frags: direct bf16 pack loads
        short8 bh[4], bl[4];
        #pragma unroll
        for (int nt = 0; nt < 4; ++nt) {
            const size_t wp = w_base + (size_t)nt * 16 * 1024 + k0;
            bh[nt] = *(const short8*)(Wh + wp);
            bl[nt] = *(const short8*)(Wl + wp);
        }
        #pragma unroll
        for (int nt = 0; nt < 4; ++nt)
            #pragma unroll
            for (int mt = 0; mt < 4; ++mt) {
                float4v t = acc[mt][nt];
                t = __builtin_amdgcn_mfma_f32_16x16x32_bf16(ah[mt], bh[nt], t, 0, 0, 0);
                t = __builtin_amdgcn_mfma_f32_16x16x32_bf16(al[mt], bh[nt], t, 0, 0, 0);
                t = __builtin_amdgcn_mfma_f32_16x16x32_bf16(ah[mt], bl[nt], t, 0, 0, 0);
                acc[mt][nt] = t;
            }
    }

    // Epilogue. C mapping (validated r6): col = l15, row = l4*4 + r.
    const int nregion = n0 >> 10;
    #pragma unroll
    for (int mt = 0; mt < 4; ++mt) {
        #pragma unroll
        for (int nt = 0; nt < 4; ++nt) {
            const int n = n0 + wn + nt * 16 + l15;
            const float bz = bias[n];
            #pragma unroll
            for (int r = 0; r < 4; ++r) {
                const int m = m0 + wm + mt * 16 + l4 * 4 + r;
                const float v = acc[mt][nt][r] + bz;
                if (mode == 1) {
                    Cout[(size_t)m * 1024 + n] = v;
                } else if (nregion == 0) {       // q -> scaled hi/lo packs
                    const float x = v * 0.125f;
                    const unsigned short hb = f2bf(x);
                    const unsigned short lb = f2bf(x - bf2f(hb));
                    const int hh = n >> 6, dd = n & 63;
                    const int t = m >> 2, bb = m & 3;
                    const size_t idx = ((size_t)(bb * 16 + hh) << 16)
                                     + (size_t)t * 64 + dd;
                    Qhi[idx] = hb; Qlo[idx] = lb;
                } else if (nregion == 1) {       // k -> hi/lo packs
                    const unsigned short hb = f2bf(v);
                    const unsigned short lb = f2bf(v - bf2f(hb));
                    const int nn = n - 1024;
                    const int hh = nn >> 6, dd = nn & 63;
                    const int t = m >> 2, bb = m & 3;
                    const size_t idx = ((size_t)(bb * 16 + hh) << 16)
                                     + (size_t)t * 64 + dd;
                    Khi[idx] = hb; Klo[idx] = lb;
                } else {                          // v -> fp32 buffer
                    Vbuf[(size_t)m * 1024 + (n - 2048)] = v;
                }
            }
        }
    }
}

// ---------------------------------------------------------------------------
// Repack fp32 v [m=(t,b)][h*64+d] -> Vthi/Vtlo bf16 [b*16+h][d][s]  (r7 valid)
// ---------------------------------------------------------------------------
__global__ __launch_bounds__(256) void repack_vt(
    const float* __restrict__ vbuf,
    unsigned short* __restrict__ Vthi, unsigned short* __restrict__ Vtlo)
{
    __shared__ float T[64][65];
    const int bh = blockIdx.x >> 4;
    const int s0 = (blockIdx.x & 15) * 64;
    const int b = bh >> 4, hh = bh & 15;
    const int tid = threadIdx.x;

    #pragma unroll
    for (int i = 0; i < 4; ++i) {
        const int s = (tid >> 4) + i * 16;
        const int d = (tid & 15) * 4;
        const float4 x = *(const float4*)&vbuf[(size_t)((s0 + s) * 4 + b) * 1024
                                               + hh * 64 + d];
        T[s][d] = x.x; T[s][d + 1] = x.y; T[s][d + 2] = x.z; T[s][d + 3] = x.w;
    }
    __syncthreads();

    const int d = tid >> 2;
    const int sg = (tid & 3) * 16;
    ushort4v hv[4], lv[4];
    #pragma unroll
    for (int k = 0; k < 16; ++k) {
        const float x = T[sg + k][d];
        const unsigned short hb = f2bf(x);
        hv[k >> 2][k & 3] = hb;
        lv[k >> 2][k & 3] = f2bf(x - bf2f(hb));
    }
    const size_t o = ((size_t)bh << 16) + (size_t)d * 1024 + s0 + sg;
    #pragma unroll
    for (int q = 0; q < 4; ++q) {
        *(ushort4v*)(Vthi + o + q * 4) = hv[q];
        *(ushort4v*)(Vtlo + o + q * 4) = lv[q];
    }
}

// ---------------------------------------------------------------------------
// Flash attention (r8, validated, unchanged). Barrier-free main loop.
// ---------------------------------------------------------------------------
__global__ __launch_bounds__(256) void attn_flash2(
    const unsigned short* __restrict__ Qhi, const unsigned short* __restrict__ Qlo,
    const unsigned short* __restrict__ Khi, const unsigned short* __restrict__ Klo,
    const unsigned short* __restrict__ Vthi, const unsigned short* __restrict__ Vtlo,
    const int* __restrict__ pad, const float* __restrict__ amask,
    float* __restrict__ attn_out,
    float* __restrict__ mfin, float* __restrict__ lfin)
{
    __shared__ __align__(16) unsigned short Ph[4][16 * 64];
    __shared__ __align__(16) unsigned short Pl[4][16 * 64];

    const int bid = blockIdx.x;
    const int tblk = bid & 15;
    const int h   = (bid >> 4) & 15;
    const int b   = bid >> 8;
    const int bh  = b * 16 + h;
    const int tid = threadIdx.x;
    const int w   = tid >> 6;
    const int l15 = tid & 15;
    const int l4  = (tid & 63) >> 4;
    const int tw  = tblk * 64 + w * 16;

    short8 qhf[2], qlf[2];
    {
        const size_t qb = ((size_t)bh << 16) + (size_t)(tw + l15) * 64 + l4 * 8;
        qhf[0] = *(const short8*)(Qhi + qb);
        qhf[1] = *(const short8*)(Qhi + qb + 32);
        qlf[0] = *(const short8*)(Qlo + qb);
        qlf[1] = *(const short8*)(Qlo + qb + 32);
    }

    float m_run = -1e30f, l_run = 0.f;
    float4v oc[4] = {{0,0,0,0},{0,0,0,0},{0,0,0,0},{0,0,0,0}};
    unsigned short* ph = Ph[w];
    unsigned short* pl = Pl[w];
    const int swz = (l15 & 7) << 3;

    for (int st = 0; st < 16; ++st) {
        const int s0 = st * 64;

        float4v c[4];
        #pragma unroll
        for (int sub = 0; sub < 4; ++sub) {
            const size_t kb = ((size_t)bh << 16)
                            + (size_t)(s0 + sub * 16 + l15) * 64 + l4 * 8;
            const short8 kh0 = *(const short8*)(Khi + kb);
            const short8 kh1 = *(const short8*)(Khi + kb + 32);
            const short8 kl0 = *(const short8*)(Klo + kb);
            const short8 kl1 = *(const short8*)(Klo + kb + 32);
            float4v cc = {0.f, 0.f, 0.f, 0.f};
            cc = __builtin_amdgcn_mfma_f32_16x16x32_bf16(kh0, qhf[0], cc, 0, 0, 0);
            cc = __builtin_amdgcn_mfma_f32_16x16x32_bf16(kh1, qhf[1], cc, 0, 0, 0);
            cc = __builtin_amdgcn_mfma_f32_16x16x32_bf16(kl0, qhf[0], cc, 0, 0, 0);
            cc = __builtin_amdgcn_mfma_f32_16x16x32_bf16(kl1, qhf[1], cc, 0, 0, 0);
            cc = __builtin_amdgcn_mfma_f32_16x16x32_bf16(kh0, qlf[0], cc, 0, 0, 0);
            cc = __builtin_amdgcn_mfma_f32_16x16x32_bf16(kh1, qlf[1], cc, 0, 0, 0);
            c[sub] = cc;
        }

        float p[4][4];
        float tmax = -1e30f;
        #pragma unroll
        for (int sub = 0; sub < 4; ++sub) {
            const int sbase = s0 + sub * 16 + l4 * 4;
            const float4 am = *(const float4*)(amask + (size_t)(tw + l15) * SSEQ + sbase);
            const int4  pd = *(const int4*)(pad + b * SSEQ + sbase);
            const float amr[4] = {am.x, am.y, am.z, am.w};
            const int   pdr[4] = {pd.x, pd.y, pd.z, pd.w};
            #pragma unroll
            for (int r = 0; r < 4; ++r) {
                const float sf = c[sub][r] + amr[r] + (pdr[r] ? -1e30f : 0.f);
                p[sub][r] = sf;
                tmax = fmaxf(tmax, sf);
            }
        }
        tmax = fmaxf(tmax, __shfl_xor(tmax, 16));
        tmax = fmaxf(tmax, __shfl_xor(tmax, 32));
        const float mnew = fmaxf(m_run, tmax);
        const float sc = __expf(m_run - mnew);
        m_run = mnew;

        float lsum = 0.f;
        #pragma unroll
        for (int sub = 0; sub < 4; ++sub)
            #pragma unroll
            for (int r = 0; r < 4; ++r) {
                const float pv = __expf(p[sub][r] - mnew);
                p[sub][r] = pv;
                lsum += pv;
            }
        l_run = l_run * sc + lsum;

        #pragma unroll
        for (int sub = 0; sub < 4; ++sub) {
            ushort4v hq, lq;
            #pragma unroll
            for (int r = 0; r < 4; ++r) {
                const unsigned short hb = f2bf(p[sub][r]);
                hq[r] = hb;
                lq[r] = f2bf(p[sub][r] - bf2f(hb));
            }
            const int col = (sub * 16 + l4 * 4) ^ swz;
            *(ushort4v*)&ph[l15 * 64 + col] = hq;
            *(ushort4v*)&pl[l15 * 64 + col] = lq;
        }
        asm volatile("s_waitcnt lgkmcnt(0)" ::: "memory");
        __builtin_amdgcn_sched_barrier(0);

        short8 pah[2], pal[2];
        #pragma unroll
        for (int kh = 0; kh < 2; ++kh) {
            const int col = (kh * 32 + l4 * 8) ^ swz;
            pah[kh] = *(const short8*)&ph[l15 * 64 + col];
            pal[kh] = *(const short8*)&pl[l15 * 64 + col];
        }

        float scr[4];
        #pragma unroll
        for (int r = 0; r < 4; ++r) scr[r] = __shfl(sc, l4 * 4 + r);
        #pragma unroll
        for (int ds = 0; ds < 4; ++ds)
            #pragma unroll
            for (int r = 0; r < 4; ++r)
                oc[ds][r] *= scr[r];

        #pragma unroll
        for (int ds = 0; ds < 4; ++ds) {
            const size_t vb = ((size_t)bh << 16)
                            + (size_t)(ds * 16 + l15) * 1024 + s0 + l4 * 8;
            const short8 vh0 = *(const short8*)(Vthi + vb);
            const short8 vh1 = *(const short8*)(Vthi + vb + 32);
            const short8 vl0 = *(const short8*)(Vtlo + vb);
            const short8 vl1 = *(const short8*)(Vtlo + vb + 32);
            float4v t = oc[ds];
            t = __builtin_amdgcn_mfma_f32_16x16x32_bf16(pah[0], vh0, t, 0, 0, 0);
            t = __builtin_amdgcn_mfma_f32_16x16x32_bf16(pah[1], vh1, t, 0, 0, 0);
            t = __builtin_amdgcn_mfma_f32_16x16x32_bf16(pal[0], vh0, t, 0, 0, 0);
            t = __builtin_amdgcn_mfma_f32_16x16x32_bf16(pal[1], vh1, t, 0, 0, 0);
            t = __builtin_amdgcn_mfma_f32_16x16x32_bf16(pah[0], vl0, t, 0, 0, 0);
            t = __builtin_amdgcn_mfma_f32_16x16x32_bf16(pah[1], vl1, t, 0, 0, 0);
            oc[ds] = t;
        }
    }

    l_run += __shfl_xor(l_run, 16);
    l_run += __shfl_xor(l_run, 32);
    if (l4 == 0) {
        mfin[bh * 1024 + tw + l15] = m_run;
        lfin[bh * 1024 + tw + l15] = l_run;
    }
    float invL[4];
    #pragma unroll
    for (int r = 0; r < 4; ++r) invL[r] = 1.0f / __shfl(l_run, l4 * 4 + r);

    #pragma unroll
    for (int ds = 0; ds < 4; ++ds)
        #pragma unroll
        for (int r = 0; r < 4; ++r) {
            const int t = tw + l4 * 4 + r;
            attn_out[(size_t)(t * 4 + b) * 1024 + h * 64 + ds * 16 + l15]
                = oc[ds][r] * invL[r];
        }
}

// ---------------------------------------------------------------------------
// avg_weights: block=(b, 32 t-rows, 256-s chunk), grid 512; wave w owns a
// 64-s strip x 32 t (2 t-subtiles). Halves K-pack traffic vs r8 (t-tile 2x).
// ---------------------------------------------------------------------------
__global__ __launch_bounds__(256) void attn_avg2(
    const unsigned short* __restrict__ Qhi, const unsigned short* __restrict__ Qlo,
    const unsigned short* __restrict__ Khi, const unsigned short* __restrict__ Klo,
    const int* __restrict__ pad, const float* __restrict__ amask,
    const float* __restrict__ mfin, const float* __restrict__ lfin,
    float* __restrict__ avg)
{
    const int bid = blockIdx.x;
    const int sq = bid & 3;
    const int tt = (bid >> 2) & 31;
    const int b  = bid >> 7;
    const int t0 = tt * 32;
    const int tid = threadIdx.x;
    const int w   = tid >> 6;
    const int l15 = tid & 15;
    const int l4  = (tid & 63) >> 4;
    const int sw0 = sq * 256 + w * 64;

    // hoist amask + pad (head-independent); [tsub][ssub][r]
    float amr[2][4][4];
    #pragma unroll
    for (int tsub = 0; tsub < 2; ++tsub) {
        const int t = t0 + tsub * 16 + l15;
        #pragma unroll
        for (int ssub = 0; ssub < 4; ++ssub) {
            const int sbase = sw0 + ssub * 16 + l4 * 4;
            const float4 am = *(const float4*)(amask + (size_t)t * SSEQ + sbase);
            const int4  pd = *(const int4*)(pad + b * SSEQ + sbase);
            amr[tsub][ssub][0] = am.x + (pd.x ? -1e30f : 0.f);
            amr[tsub][ssub][1] = am.y + (pd.y ? -1e30f : 0.f);
            amr[tsub][ssub][2] = am.z + (pd.z ? -1e30f : 0.f);
            amr[tsub][ssub][3] = am.w + (pd.w ? -1e30f : 0.f);
        }
    }

    float acc[2][4][4] = {};

    for (int hh = 0; hh < NH; ++hh) {
        const int bh = b * 16 + hh;
        short8 qhf[2][2], qlf[2][2];
        float m[2], il[2];
        #pragma unroll
        for (int tsub = 0; tsub < 2; ++tsub) {
            const size_t qb = ((size_t)bh << 16)
                            + (size_t)(t0 + tsub * 16 + l15) * 64 + l4 * 8;
            qhf[tsub][0] = *(const short8*)(Qhi + qb);
            qhf[tsub][1] = *(const short8*)(Qhi + qb + 32);
            qlf[tsub][0] = *(const short8*)(Qlo + qb);
            qlf[tsub][1] = *(const short8*)(Qlo + qb + 32);
            m[tsub]  = mfin[bh * 1024 + t0 + tsub * 16 + l15];
            il[tsub] = 1.0f / lfin[bh * 1024 + t0 + tsub * 16 + l15];
        }

        #pragma unroll
        for (int ssub = 0; ssub < 4; ++ssub) {
            const size_t kb = ((size_t)bh << 16)
                            + (size_t)(sw0 + ssub * 16 + l15) * 64 + l4 * 8;
            const short8 kh0 = *(const short8*)(Khi + kb);
            const short8 kh1 = *(const short8*)(Khi + kb + 32);
            const short8 kl0 = *(const short8*)(Klo + kb);
            const short8 kl1 = *(const short8*)(Klo + kb + 32);
            #pragma unroll
            for (int tsub = 0; tsub < 2; ++tsub) {
                float4v cc = {0.f, 0.f, 0.f, 0.f};
                cc = __builtin_amdgcn_mfma_f32_16x16x32_bf16(kh0, qhf[tsub][0], cc, 0, 0, 0);
                cc = __builtin_amdgcn_mfma_f32_16x16x32_bf16(kh1, qhf[tsub][1], cc, 0, 0, 0);
                cc = __builtin_amdgcn_mfma_f32_16x16x32_bf16(kl0, qhf[tsub][0], cc, 0, 0, 0);
                cc = __builtin_amdgcn_mfma_f32_16x16x32_bf16(kl1, qhf[tsub][1], cc, 0, 0, 0);
                cc = __builtin_amdgcn_mfma_f32_16x16x32_bf16(kh0, qlf[tsub][0], cc, 0, 0, 0);
                cc = __builtin_amdgcn_mfma_f32_16x16x32_bf16(kh1, qlf[tsub][1], cc, 0, 0, 0);
                #pragma unroll
                for (int r = 0; r < 4; ++r)
                    acc[tsub][ssub][r]
                        += __expf(cc[r] + amr[tsub][ssub][r] - m[tsub]) * il[tsub];
            }
        }
    }

    const float ivH = 1.0f / NH;
    #pragma unroll
    for (int tsub = 0; tsub < 2; ++tsub) {
        const int t = t0 + tsub * 16 + l15;
        #pragma unroll
        for (int ssub = 0; ssub < 4; ++ssub) {
            float4 o;
            o.x = acc[tsub][ssub][0] * ivH; o.y = acc[tsub][ssub][1] * ivH;
            o.z = acc[tsub][ssub][2] * ivH; o.w = acc[tsub][ssub][3] * ivH;
            *(float4*)&avg[(size_t)(b * 1024 + t) * 1024
                           + sw0 + ssub * 16 + l4 * 4] = o;
        }
    }
}

// ---------------------------------------------------------------------------
extern "C" void kernel_launch(void* const* d_in, const int* in_sizes, int n_in,
                              void* d_out, int out_size, void* d_ws, size_t ws_size,
                              hipStream_t stream) {
    const float* query = (const float*)d_in[0];
    const float* key   = (const float*)d_in[1];
    const float* value = (const float*)d_in[2];
    const int*   pad   = (const int*)d_in[3];
    const float* amask = (const float*)d_in[4];
    const float* wqkv  = (const float*)d_in[5];
    const float* bqkv  = (const float*)d_in[6];
    const float* wout  = (const float*)d_in[7];
    const float* bout  = (const float*)d_in[8];

    float* out = (float*)d_out;
    float* avg = out + (size_t)TSEQ * BATCH * EMBED;

    // ws layout, 67,633,152 B total == r7/r8 proven budget.
    //   vbuf fp32 16.78MB (aliased as attn_out after repack consumes it)
    //   Qhi/Qlo/Khi/Klo packs 4 x 8.39MB
    //   mfin/lfin 0.5MB
    //   T region 16.78MB, time-multiplexed:
    //     Wqkv packs (stages 1-2) -> Vt packs (3-4) -> Wout packs (5-7)
    float* vbuf = (float*)d_ws;
    unsigned short* Qhi = (unsigned short*)(vbuf + 4194304);
    unsigned short* Qlo = Qhi + 4194304;
    unsigned short* Khi = Qlo + 4194304;
    unsigned short* Klo = Khi + 4194304;
    float* mfin = (float*)(Klo + 4194304);
    float* lfin = mfin + 65536;
    unsigned short* Treg = (unsigned short*)(lfin + 65536);
    unsigned short* Wqh  = Treg;                 // 3072*1024
    unsigned short* Wql  = Treg + 3145728;
    unsigned short* Vthi = Treg;                 // 64*64*1024
    unsigned short* Vtlo = Treg + 4194304;
    unsigned short* Woh  = Treg;                 // 1024*1024
    unsigned short* Wol  = Treg + 1048576;
    float* attn = vbuf;   // alias: repack reads vbuf before flash2 writes attn

    // 1) W_qkv -> hi/lo packs
    conv_hilo<<<dim3(3072), 256, 0, stream>>>(wqkv, Wqh, Wql, 3072 * 1024 / 4);

    // 2) QKV projection (MFMA) -> Q/K packs + vbuf
    gemm_mfma<<<dim3(24, 32), 256, 0, stream>>>(query, key, value, Wqh, Wql,
                                                bqkv, 0, Qhi, Qlo, Khi, Klo,
                                                vbuf, nullptr);

    // 3) V transpose/pack (overwrites dead Wqkv packs)
    repack_vt<<<dim3(1024), 256, 0, stream>>>(vbuf, Vthi, Vtlo);

    // 4) flash attention
    attn_flash2<<<dim3(1024), 256, 0, stream>>>(Qhi, Qlo, Khi, Klo, Vthi, Vtlo,
                                                pad, amask, attn, mfin, lfin);

    // 5) W_out -> hi/lo packs (overwrites dead Vt packs)
    conv_hilo<<<dim3(1024), 256, 0, stream>>>(wout, Woh, Wol, 1024 * 1024 / 4);

    // 6) avg_weights
    attn_avg2<<<dim3(512), 256, 0, stream>>>(Qhi, Qlo, Khi, Klo, pad, amask,
                                             mfin, lfin, avg);

    // 7) output projection (MFMA)
    gemm_mfma<<<dim3(8, 32), 256, 0, stream>>>(attn, attn, attn, Woh, Wol,
                                               bout, 1, nullptr, nullptr,
                                               nullptr, nullptr, nullptr, out);
}